// Round 3
// baseline (399.384 us; speedup 1.0000x reference)
//
#include <hip/hip_runtime.h>

// B=16, C=256, H=W=64 -> N=4096, NH=4, HD=64, G=32 (8 ch/group), K=256
// ALL inputs and d_out are FP32 (reference dtypes). Internal: bf16 + fp32 acc.
// qkv rows: o in [0,768): q=[0,256), k=[256,512), v=[512,768)
// Workspace (total 101,744,640 B):
//   qkv  : (o, b*N + n)   768 x 65536 bf16   = 100,663,296 B  at +0
//   ctx  : (b*4+h, e, d)  64 x 64 x 64 fp32  =   1,048,576 B  at +100663296
//   scsh : (b, c) float2  16 x 256           =      32,768 B  at +101711872
// out2 (attention output, (c, b*N+n) bf16) reuses qkv rows [256,512) (old k).

typedef __bf16 bf16x8 __attribute__((ext_vector_type(8)));
typedef __bf16 bf16x4 __attribute__((ext_vector_type(4)));
typedef float  f32x4  __attribute__((ext_vector_type(4)));

__device__ __forceinline__ float wave_red_sum(float v) {
#pragma unroll
    for (int off = 32; off > 0; off >>= 1) v += __shfl_xor(v, off, 64);
    return v;
}
__device__ __forceinline__ float wave_red_max(float v) {
#pragma unroll
    for (int off = 32; off > 0; off >>= 1) v = fmaxf(v, __shfl_xor(v, off, 64));
    return v;
}

// ---------------------------------------------------------------------------
// GroupNorm stats: per (b,g) mean/rstd -> per-channel (sc, sh) in scsh[b*256+c]
// grid 512 = (b 16) x (g 32); block 256; 32768 fp32 per group
// ---------------------------------------------------------------------------
__global__ __launch_bounds__(256)
void gn_stats_kernel(const float* __restrict__ x, const float* __restrict__ gw,
                     const float* __restrict__ gb, float2* __restrict__ scsh)
{
    const int blk = blockIdx.x;
    const int b = blk >> 5, g = blk & 31;
    const int tid = threadIdx.x;
    const int lane = tid & 63, wid = tid >> 6;
    const size_t xbase = ((size_t)(b * 256 + g * 8)) * 4096;

    float s1 = 0.f, s2 = 0.f;
#pragma unroll
    for (int it = 0; it < 32; it++) {
        const int idx = (it * 256 + tid) * 4;
        const float4 v4 = *(const float4*)(x + xbase + idx);
        s1 += v4.x + v4.y + v4.z + v4.w;
        s2 += v4.x * v4.x + v4.y * v4.y + v4.z * v4.z + v4.w * v4.w;
    }
    __shared__ float red[8];
    float s1w = wave_red_sum(s1);
    float s2w = wave_red_sum(s2);
    if (lane == 0) { red[wid] = s1w; red[4 + wid] = s2w; }
    __syncthreads();
    const float mean = (red[0] + red[1] + red[2] + red[3]) * (1.0f / 32768.0f);
    const float ms   = (red[4] + red[5] + red[6] + red[7]) * (1.0f / 32768.0f);
    const float inv  = rsqrtf(fmaxf(ms - mean * mean, 0.f) + 1e-5f);

    if (tid < 8) {
        const int c = g * 8 + tid;
        const float sc = gw[c] * inv;
        const float sh = gb[c] - mean * sc;
        scsh[b * 256 + c] = make_float2(sc, sh);
    }
}

// ---------------------------------------------------------------------------
// GEMM: C[M x 65536] = A[M x 256] @ B[256 x 65536]; A fp32 (weights),
// bf16 MFMA, fp32 acc. Tile 128x128, BK=32, 4 waves, 4x4 16x16x32 per wave.
// SECOND=false: B = x fp32 (b,c,n) + fused GroupNorm; C -> qkv bf16 rows.
// SECOND=true : B = out2 bf16 (c,b*N+n); C -> d_out fp32 (b,c,n) + bias + x.
// ---------------------------------------------------------------------------
template<bool SECOND>
__global__ __launch_bounds__(256)
void gemm_kernel(const float* __restrict__ A,
                 const void* __restrict__ Bsrc,
                 const float* __restrict__ bias,
                 const float* __restrict__ xres,
                 const float2* __restrict__ scsh,
                 void* __restrict__ Cout)
{
    constexpr int KDIM = 256;
    constexpr int NTOT = 65536;
    __shared__ __align__(16) __bf16 lds_a[128 * 40];   // [m][k] stride 40
    __shared__ __align__(16) __bf16 lds_b[32 * 130];   // [k][n] stride 130

    const int tid  = threadIdx.x;
    const int lane = tid & 63;
    const int wid  = tid >> 6;
    const int quad = lane >> 4;
    const int tcol = lane & 15;
    const int wm   = (wid & 1) * 64;
    const int wn   = (wid >> 1) * 64;
    const int n0   = blockIdx.x * 128;
    const int m0   = blockIdx.y * 128;

    f32x4 acc[4][4];
#pragma unroll
    for (int i = 0; i < 4; i++)
#pragma unroll
        for (int j = 0; j < 4; j++) acc[i][j] = {0.f, 0.f, 0.f, 0.f};

    const int arow = tid >> 1, akq = (tid & 1) * 16;
    const int bk   = tid >> 3, bn  = (tid & 7) * 16;

    for (int kt = 0; kt < KDIM; kt += 32) {
        __syncthreads();
        {   // stage A tile 128x32: fp32 -> bf16
            const float* src = A + (size_t)(m0 + arow) * KDIM + kt + akq;
            float4 f0 = *(const float4*)(src);
            float4 f1 = *(const float4*)(src + 4);
            float4 f2 = *(const float4*)(src + 8);
            float4 f3 = *(const float4*)(src + 12);
            bf16x8 o0, o1;
            o0[0]=(__bf16)f0.x; o0[1]=(__bf16)f0.y; o0[2]=(__bf16)f0.z; o0[3]=(__bf16)f0.w;
            o0[4]=(__bf16)f1.x; o0[5]=(__bf16)f1.y; o0[6]=(__bf16)f1.z; o0[7]=(__bf16)f1.w;
            o1[0]=(__bf16)f2.x; o1[1]=(__bf16)f2.y; o1[2]=(__bf16)f2.z; o1[3]=(__bf16)f2.w;
            o1[4]=(__bf16)f3.x; o1[5]=(__bf16)f3.y; o1[6]=(__bf16)f3.z; o1[7]=(__bf16)f3.w;
            *(bf16x8*)&lds_a[arow * 40 + akq]     = o0;
            *(bf16x8*)&lds_a[arow * 40 + akq + 8] = o1;
        }
        if (!SECOND) {   // stage B from fp32 x (b,c,n), GroupNorm fused
            const int b  = n0 >> 12;
            const int nn = n0 & 4095;
            const int c  = kt + bk;
            const float2 ss = scsh[b * 256 + c];
            const float* src = (const float*)Bsrc + ((size_t)(b * 256 + c)) * 4096 + nn + bn;
            float4 f0 = *(const float4*)(src);
            float4 f1 = *(const float4*)(src + 4);
            float4 f2 = *(const float4*)(src + 8);
            float4 f3 = *(const float4*)(src + 12);
            bf16x8 o0, o1;
            o0[0]=(__bf16)(f0.x*ss.x+ss.y); o0[1]=(__bf16)(f0.y*ss.x+ss.y);
            o0[2]=(__bf16)(f0.z*ss.x+ss.y); o0[3]=(__bf16)(f0.w*ss.x+ss.y);
            o0[4]=(__bf16)(f1.x*ss.x+ss.y); o0[5]=(__bf16)(f1.y*ss.x+ss.y);
            o0[6]=(__bf16)(f1.z*ss.x+ss.y); o0[7]=(__bf16)(f1.w*ss.x+ss.y);
            o1[0]=(__bf16)(f2.x*ss.x+ss.y); o1[1]=(__bf16)(f2.y*ss.x+ss.y);
            o1[2]=(__bf16)(f2.z*ss.x+ss.y); o1[3]=(__bf16)(f2.w*ss.x+ss.y);
            o1[4]=(__bf16)(f3.x*ss.x+ss.y); o1[5]=(__bf16)(f3.y*ss.x+ss.y);
            o1[6]=(__bf16)(f3.z*ss.x+ss.y); o1[7]=(__bf16)(f3.w*ss.x+ss.y);
            uint* dst = (uint*)&lds_b[bk * 130 + bn];   // 4B-aligned
            const uint* p0 = (const uint*)&o0;
            const uint* p1 = (const uint*)&o1;
            dst[0] = p0[0]; dst[1] = p0[1]; dst[2] = p0[2]; dst[3] = p0[3];
            dst[4] = p1[0]; dst[5] = p1[1]; dst[6] = p1[2]; dst[7] = p1[3];
        } else {         // stage B tile 32x128 from bf16 (c, b*N+n) matrix
            const __bf16* src = (const __bf16*)Bsrc + (size_t)(kt + bk) * NTOT + n0 + bn;
            uint4 v0 = *(const uint4*)(src);
            uint4 v1 = *(const uint4*)(src + 8);
            uint* dst = (uint*)&lds_b[bk * 130 + bn];
            dst[0] = v0.x; dst[1] = v0.y; dst[2] = v0.z; dst[3] = v0.w;
            dst[4] = v1.x; dst[5] = v1.y; dst[6] = v1.z; dst[7] = v1.w;
        }
        __syncthreads();

        bf16x8 af[4];
#pragma unroll
        for (int mi = 0; mi < 4; mi++)
            af[mi] = *(const bf16x8*)&lds_a[(wm + mi * 16 + tcol) * 40 + quad * 8];
        bf16x8 bfr[4];
#pragma unroll
        for (int ni = 0; ni < 4; ni++) {
            bf16x8 t;
#pragma unroll
            for (int j = 0; j < 8; j++)
                t[j] = lds_b[(quad * 8 + j) * 130 + wn + ni * 16 + tcol];
            bfr[ni] = t;
        }
#pragma unroll
        for (int mi = 0; mi < 4; mi++)
#pragma unroll
            for (int ni = 0; ni < 4; ni++)
                acc[mi][ni] = __builtin_amdgcn_mfma_f32_16x16x32_bf16(
                    af[mi], bfr[ni], acc[mi][ni], 0, 0, 0);
    }

    // epilogue: C/D layout col = lane&15 (N), row = quad*4 + r (M)
#pragma unroll
    for (int mi = 0; mi < 4; mi++) {
#pragma unroll
        for (int r = 0; r < 4; r++) {
            const int grow = m0 + wm + mi * 16 + quad * 4 + r;
            const float bv = bias[grow];
#pragma unroll
            for (int ni = 0; ni < 4; ni++) {
                const int gcol = n0 + wn + ni * 16 + tcol;
                float v = acc[mi][ni][r] + bv;
                if (SECOND) {
                    const int b = gcol >> 12, n = gcol & 4095;
                    const size_t oidx = ((size_t)(b * 256 + grow)) * 4096 + n;
                    ((float*)Cout)[oidx] = v + xres[oidx];
                } else {
                    ((__bf16*)Cout)[(size_t)grow * NTOT + gcol] = (__bf16)v;
                }
            }
        }
    }
}

// ---------------------------------------------------------------------------
// q softmax over n (4096) — one block per (o,b) row, in place on qkv rows 0..255
// ---------------------------------------------------------------------------
__global__ __launch_bounds__(256)
void softmax_q(__bf16* __restrict__ qkv)
{
    const int o = blockIdx.x >> 4;     // 0..255
    const int b = blockIdx.x & 15;
    const int tid = threadIdx.x;
    const int lane = tid & 63, wid = tid >> 6;
    const size_t base = (size_t)o * 65536 + (size_t)b * 4096;

    float v[16];
    float m = -INFINITY;
#pragma unroll
    for (int s = 0; s < 16; s++) {
        v[s] = (float)qkv[base + s * 256 + tid];
        m = fmaxf(m, v[s]);
    }
    __shared__ float red[4];
    float wmx = wave_red_max(m);
    if (lane == 0) red[wid] = wmx;
    __syncthreads();
    m = fmaxf(fmaxf(red[0], red[1]), fmaxf(red[2], red[3]));
    __syncthreads();
    float sum = 0.f;
#pragma unroll
    for (int s = 0; s < 16; s++) { v[s] = __expf(v[s] - m); sum += v[s]; }
    float wsm = wave_red_sum(sum);
    if (lane == 0) red[wid] = wsm;
    __syncthreads();
    const float inv = 1.0f / (red[0] + red[1] + red[2] + red[3]);
#pragma unroll
    for (int s = 0; s < 16; s++)
        qkv[base + s * 256 + tid] = (__bf16)(v[s] * inv);
}

// ---------------------------------------------------------------------------
// k softmax over d (64, stride 65536) — one thread per (b,h,n), in place
// ---------------------------------------------------------------------------
__global__ __launch_bounds__(256)
void softmax_k(__bf16* __restrict__ qkv)
{
    const int idx = blockIdx.x * 256 + threadIdx.x;  // 0..262143
    const int n = idx & 4095;
    const int hh = (idx >> 12) & 3;
    const int b = idx >> 14;
    const size_t base = (size_t)(256 + hh * 64) * 65536 + (size_t)b * 4096 + n;

    float v[64];
    float m = -INFINITY;
#pragma unroll
    for (int d = 0; d < 64; d++) {
        v[d] = (float)qkv[base + (size_t)d * 65536];
        m = fmaxf(m, v[d]);
    }
    float s = 0.f;
#pragma unroll
    for (int d = 0; d < 64; d++) { v[d] = __expf(v[d] - m); s += v[d]; }
    const float inv = 1.0f / s;
#pragma unroll
    for (int d = 0; d < 64; d++)
        qkv[base + (size_t)d * 65536] = (__bf16)(v[d] * inv);
}

// ---------------------------------------------------------------------------
// ctx[bh][e][d] = sum_n v[e][n] * k_sm[d][n]; split over n with atomics.
// grid 512 = (bh 64) x (kc 8); block 256; per block n-range = 512
// ---------------------------------------------------------------------------
__global__ __launch_bounds__(256)
void ctx_kernel(const __bf16* __restrict__ qkv, float* __restrict__ ctx)
{
    const int bh = blockIdx.x >> 3, kc = blockIdx.x & 7;
    const int b = bh >> 2, hh = bh & 3;
    const int n_start = kc * 512;
    __shared__ __align__(16) __bf16 lk[64 * 68], lv[64 * 68];
    const int tid = threadIdx.x;
    const int te = tid & 15, td = tid >> 4;
    const int e0 = te * 4, d0 = td * 4;
    float acc[4][4] = {};

    const size_t kbase = (size_t)(256 + hh * 64) * 65536 + (size_t)b * 4096;
    const size_t vbase = (size_t)(512 + hh * 64) * 65536 + (size_t)b * 4096;
    const int sd = tid >> 2, sn = (tid & 3) * 16;

    for (int nc = 0; nc < 512; nc += 64) {
        __syncthreads();
        {
            const __bf16* ks = qkv + kbase + (size_t)sd * 65536 + n_start + nc + sn;
            uint4 a0 = *(const uint4*)ks; uint4 a1 = *(const uint4*)(ks + 8);
            uint* kd = (uint*)&lk[sd * 68 + sn];
            kd[0]=a0.x; kd[1]=a0.y; kd[2]=a0.z; kd[3]=a0.w;
            kd[4]=a1.x; kd[5]=a1.y; kd[6]=a1.z; kd[7]=a1.w;
            const __bf16* vs = qkv + vbase + (size_t)sd * 65536 + n_start + nc + sn;
            uint4 c0 = *(const uint4*)vs; uint4 c1 = *(const uint4*)(vs + 8);
            uint* vd = (uint*)&lv[sd * 68 + sn];
            vd[0]=c0.x; vd[1]=c0.y; vd[2]=c0.z; vd[3]=c0.w;
            vd[4]=c1.x; vd[5]=c1.y; vd[6]=c1.z; vd[7]=c1.w;
        }
        __syncthreads();
#pragma unroll
        for (int n4 = 0; n4 < 64; n4 += 4) {
            bf16x4 kq[4], vq[4];
#pragma unroll
            for (int j = 0; j < 4; j++) {
                kq[j] = *(const bf16x4*)&lk[(d0 + j) * 68 + n4];
                vq[j] = *(const bf16x4*)&lv[(e0 + j) * 68 + n4];
            }
            float kf[4][4], vf[4][4];
#pragma unroll
            for (int j = 0; j < 4; j++)
#pragma unroll
                for (int t = 0; t < 4; t++) {
                    kf[j][t] = (float)kq[j][t];
                    vf[j][t] = (float)vq[j][t];
                }
#pragma unroll
            for (int i = 0; i < 4; i++)
#pragma unroll
                for (int j = 0; j < 4; j++)
#pragma unroll
                    for (int t = 0; t < 4; t++)
                        acc[i][j] += vf[i][t] * kf[j][t];
        }
    }
    float* cb = ctx + (size_t)bh * 4096;
#pragma unroll
    for (int i = 0; i < 4; i++)
#pragma unroll
        for (int j = 0; j < 4; j++)
            atomicAdd(&cb[(e0 + i) * 64 + (d0 + j)], acc[i][j]);
}

// ---------------------------------------------------------------------------
// out2[e][b*N+n] = sum_d ctx[e][d] * q_sm[d][n]  (per (b,h))
// out2 base points at qkv rows [256,512) (k region, already consumed).
// grid 1024 = (b 16) x (h 4) x (nc 16); block 256; thread = one n
// ---------------------------------------------------------------------------
__global__ __launch_bounds__(256)
void av_kernel(const __bf16* __restrict__ qkv, const float* __restrict__ ctx,
               __bf16* __restrict__ out2)
{
    const int b  = blockIdx.x >> 6;
    const int hh = (blockIdx.x >> 4) & 3;
    const int nc = blockIdx.x & 15;
    const int tid = threadIdx.x;
    const int n = nc * 256 + tid;

    __shared__ __align__(16) float lctx[4096];
    const float* csrc = ctx + (size_t)(b * 4 + hh) * 4096;
#pragma unroll
    for (int i = 0; i < 4; i++)
        ((float4*)lctx)[tid + i * 256] = ((const float4*)csrc)[tid + i * 256];
    __syncthreads();

    float acc[64];
#pragma unroll
    for (int e = 0; e < 64; e++) acc[e] = 0.f;

    const size_t qbase = (size_t)(hh * 64) * 65536 + (size_t)b * 4096 + n;
#pragma unroll 4
    for (int d4 = 0; d4 < 64; d4 += 4) {
        const float q0 = (float)qkv[qbase + (size_t)(d4 + 0) * 65536];
        const float q1 = (float)qkv[qbase + (size_t)(d4 + 1) * 65536];
        const float q2 = (float)qkv[qbase + (size_t)(d4 + 2) * 65536];
        const float q3 = (float)qkv[qbase + (size_t)(d4 + 3) * 65536];
#pragma unroll
        for (int e = 0; e < 64; e++) {
            const float4 c4 = *(const float4*)&lctx[e * 64 + d4];
            acc[e] += c4.x * q0 + c4.y * q1 + c4.z * q2 + c4.w * q3;
        }
    }
    const size_t obase = (size_t)(hh * 64) * 65536 + (size_t)b * 4096 + n;
#pragma unroll
    for (int e = 0; e < 64; e++)
        out2[obase + (size_t)e * 65536] = (__bf16)acc[e];
}

// ---------------------------------------------------------------------------
extern "C" void kernel_launch(void* const* d_in, const int* in_sizes, int n_in,
                              void* d_out, int out_size, void* d_ws, size_t ws_size,
                              hipStream_t stream)
{
    const float* x     = (const float*)d_in[0];
    const float* gn_w  = (const float*)d_in[1];
    const float* gn_b  = (const float*)d_in[2];
    const float* qkv_w = (const float*)d_in[3];
    const float* qkv_b = (const float*)d_in[4];
    const float* out_w = (const float*)d_in[5];
    const float* out_b = (const float*)d_in[6];
    float* out = (float*)d_out;

    char* ws = (char*)d_ws;
    __bf16* qkv  = (__bf16*)ws;                                   // 100,663,296 B
    float*  ctx  = (float*)(ws + (size_t)100663296);              //   1,048,576 B
    float2* scsh = (float2*)(ws + (size_t)100663296 + 1048576);   //      32,768 B
    __bf16* out2 = qkv + (size_t)256 * 65536;                     // reuse k rows

    hipMemsetAsync(ctx, 0, 262144 * sizeof(float), stream);
    gn_stats_kernel<<<512, 256, 0, stream>>>(x, gn_w, gn_b, scsh);
    gemm_kernel<false><<<dim3(512, 6), 256, 0, stream>>>(qkv_w, x, qkv_b, nullptr, scsh, qkv);
    softmax_q<<<4096, 256, 0, stream>>>(qkv);
    softmax_k<<<1024, 256, 0, stream>>>(qkv);
    ctx_kernel<<<512, 256, 0, stream>>>(qkv, ctx);
    av_kernel<<<1024, 256, 0, stream>>>(qkv, ctx, out2);
    gemm_kernel<true><<<dim3(512, 2), 256, 0, stream>>>(out_w, out2, out_b, x, nullptr, out);
}

// Round 4
// 348.053 us; speedup vs baseline: 1.1475x; 1.1475x over previous
//
#include <hip/hip_runtime.h>

// B=16, C=256, H=W=64 -> N=4096, NH=4, HD=64, G=32 (8 ch/group), K=256
// ALL inputs and d_out are FP32. Internal: bf16 operands + fp32 acc.
// qkv rows: o in [0,768): q=[0,256), k=[256,512), v=[512,768)
// Workspace (101,744,640 B total, same as round 3):
//   qkv  : (o, b*N + n)   768 x 65536 bf16  = 100,663,296 B at +0
//   ctx  : (b*4+h, e, d)  64 x 64 x 64 fp32 =   1,048,576 B at +100663296
//   scsh : (b, c) float2  16 x 256          =      32,768 B at +101711872
//   W2   : (b, o, c') 16x256x256 bf16 (2 MB) reuses qkv k-rows region (+33554432 B)
// Pipeline: gn_stats -> gemm1(GN fused) -> softmax_q -> ctx(k-softmax fused)
//           -> w2 (out_w @ ctx^T) -> gemm2 (W2[b] @ q + bias + residual)

typedef __bf16 bf16x8 __attribute__((ext_vector_type(8)));
typedef __bf16 bf16x4 __attribute__((ext_vector_type(4)));
typedef float  f32x4  __attribute__((ext_vector_type(4)));

__device__ __forceinline__ float wave_red_sum(float v) {
#pragma unroll
    for (int off = 32; off > 0; off >>= 1) v += __shfl_xor(v, off, 64);
    return v;
}
__device__ __forceinline__ float wave_red_max(float v) {
#pragma unroll
    for (int off = 32; off > 0; off >>= 1) v = fmaxf(v, __shfl_xor(v, off, 64));
    return v;
}

// ---------------------------------------------------------------------------
// GroupNorm stats -> per-channel (sc, sh); grid 512 = (b16 x g32), block 256
// ---------------------------------------------------------------------------
__global__ __launch_bounds__(256)
void gn_stats_kernel(const float* __restrict__ x, const float* __restrict__ gw,
                     const float* __restrict__ gb, float2* __restrict__ scsh)
{
    const int blk = blockIdx.x;
    const int b = blk >> 5, g = blk & 31;
    const int tid = threadIdx.x;
    const int lane = tid & 63, wid = tid >> 6;
    const size_t xbase = ((size_t)(b * 256 + g * 8)) * 4096;

    float s1 = 0.f, s2 = 0.f;
#pragma unroll
    for (int it = 0; it < 32; it++) {
        const int idx = (it * 256 + tid) * 4;
        const float4 v4 = *(const float4*)(x + xbase + idx);
        s1 += v4.x + v4.y + v4.z + v4.w;
        s2 += v4.x * v4.x + v4.y * v4.y + v4.z * v4.z + v4.w * v4.w;
    }
    __shared__ float red[8];
    float s1w = wave_red_sum(s1);
    float s2w = wave_red_sum(s2);
    if (lane == 0) { red[wid] = s1w; red[4 + wid] = s2w; }
    __syncthreads();
    const float mean = (red[0] + red[1] + red[2] + red[3]) * (1.0f / 32768.0f);
    const float ms   = (red[4] + red[5] + red[6] + red[7]) * (1.0f / 32768.0f);
    const float inv  = rsqrtf(fmaxf(ms - mean * mean, 0.f) + 1e-5f);

    if (tid < 8) {
        const int c = g * 8 + tid;
        const float sc = gw[c] * inv;
        const float sh = gb[c] - mean * sc;
        scsh[b * 256 + c] = make_float2(sc, sh);
    }
}

// ---------------------------------------------------------------------------
// GEMM: C[M x 65536] = A[M x 256] @ B[256 x 65536]. One block per 128-col
// tile; full-K B^T staged ONCE in LDS (k-contiguous rows, XOR swizzle), then
// loop over all M tiles (MT = M/128). bf16 MFMA 16x16x32, fp32 acc.
// SECOND=false: A = qkv_w fp32; B = x fp32 w/ fused GN; C -> qkv bf16.  MT=6
// SECOND=true : A = W2[b] bf16; B = q rows bf16; C -> d_out fp32 +bias+x. MT=2
// ---------------------------------------------------------------------------
template<bool SECOND>
__global__ __launch_bounds__(256)
void gemm_kernel(const void* __restrict__ Av,
                 const void* __restrict__ Bsrc,
                 const float* __restrict__ bias,
                 const float* __restrict__ xres,
                 const float2* __restrict__ scsh,
                 void* __restrict__ Cout)
{
    constexpr int MT = SECOND ? 2 : 6;
    __shared__ __align__(16) __bf16 lds_bt[128 * 264];  // B^T: [n][k], 67584 B
    __shared__ __align__(16) __bf16 lds_a[128 * 40];    // A:   [m][k], 10240 B
    __shared__ float2 lscsh[256];                        // 2 KB

    const int tid  = threadIdx.x;
    const int lane = tid & 63;
    const int wid  = tid >> 6;
    const int quad = lane >> 4;
    const int tcol = lane & 15;
    const int wm   = (wid & 1) * 64;
    const int wn   = (wid >> 1) * 64;
    const int n0   = blockIdx.x * 128;       // global column base
    const int b    = n0 >> 12;               // batch of this column tile
    const int nn   = n0 & 4095;

    // ---- stage B^T (full K=256) once ----
    if (!SECOND) { lscsh[tid] = scsh[b * 256 + tid]; }
    __syncthreads();

    const int sn    = tid & 127;             // tile-local column
    const int chalf = tid >> 7;              // 0/1: which 16-chunk of the 32
    const int swz   = (sn >> 3) & 3;
#pragma unroll
    for (int iter = 0; iter < 8; iter++) {
        const int cbase = iter * 32 + chalf * 16;
        bf16x8 o0, o1;
        if (!SECOND) {
            const float* xs = (const float*)Bsrc + (size_t)b * 1048576 + nn + sn;
#pragma unroll
            for (int j = 0; j < 16; j++) {
                const int c = cbase + j;
                const float2 ss = lscsh[c];
                const float f = xs[(size_t)c * 4096];
                const __bf16 v = (__bf16)(f * ss.x + ss.y);
                if (j < 8) o0[j] = v; else o1[j - 8] = v;
            }
        } else {
            const __bf16* qs = (const __bf16*)Bsrc + n0 + sn;
#pragma unroll
            for (int j = 0; j < 16; j++) {
                const int c = cbase + j;
                const __bf16 v = qs[(size_t)c * 65536];
                if (j < 8) o0[j] = v; else o1[j - 8] = v;
            }
        }
        const int chunk = iter * 2 + chalf;
        const int chSw  = chunk ^ swz;
        __bf16* dst = &lds_bt[sn * 264 + chSw * 16];
        *(bf16x8*)dst       = o0;
        *(bf16x8*)(dst + 8) = o1;
    }

    const int arow = tid >> 1, k16 = (tid & 1) * 16;

    for (int mt = 0; mt < MT; mt++) {
        const int m0 = mt * 128;
        f32x4 acc[4][4];
#pragma unroll
        for (int i = 0; i < 4; i++)
#pragma unroll
            for (int j = 0; j < 4; j++) acc[i][j] = {0.f, 0.f, 0.f, 0.f};

        for (int kt = 0; kt < 256; kt += 32) {
            __syncthreads();   // prior frag reads (or B^T staging) complete
            {   // stage A tile 128x32
                bf16x8 o0, o1;
                if (!SECOND) {
                    const float* src = (const float*)Av + (size_t)(m0 + arow) * 256 + kt + k16;
                    const float4 f0 = *(const float4*)(src);
                    const float4 f1 = *(const float4*)(src + 4);
                    const float4 f2 = *(const float4*)(src + 8);
                    const float4 f3 = *(const float4*)(src + 12);
                    o0[0]=(__bf16)f0.x; o0[1]=(__bf16)f0.y; o0[2]=(__bf16)f0.z; o0[3]=(__bf16)f0.w;
                    o0[4]=(__bf16)f1.x; o0[5]=(__bf16)f1.y; o0[6]=(__bf16)f1.z; o0[7]=(__bf16)f1.w;
                    o1[0]=(__bf16)f2.x; o1[1]=(__bf16)f2.y; o1[2]=(__bf16)f2.z; o1[3]=(__bf16)f2.w;
                    o1[4]=(__bf16)f3.x; o1[5]=(__bf16)f3.y; o1[6]=(__bf16)f3.z; o1[7]=(__bf16)f3.w;
                } else {
                    const __bf16* src = (const __bf16*)Av + (size_t)b * 65536
                                      + (size_t)(m0 + arow) * 256 + kt + k16;
                    o0 = *(const bf16x8*)(src);
                    o1 = *(const bf16x8*)(src + 8);
                }
                *(bf16x8*)&lds_a[arow * 40 + k16]     = o0;
                *(bf16x8*)&lds_a[arow * 40 + k16 + 8] = o1;
            }
            __syncthreads();

            bf16x8 af[4];
#pragma unroll
            for (int mi = 0; mi < 4; mi++)
                af[mi] = *(const bf16x8*)&lds_a[(wm + mi * 16 + tcol) * 40 + quad * 8];
            bf16x8 bfr[4];
#pragma unroll
            for (int ni = 0; ni < 4; ni++) {
                const int n = wn + ni * 16 + tcol;
                const int k = kt + quad * 8;
                const int chSw = (k >> 4) ^ ((n >> 3) & 3);
                bfr[ni] = *(const bf16x8*)&lds_bt[n * 264 + chSw * 16 + (k & 15)];
            }
#pragma unroll
            for (int mi = 0; mi < 4; mi++)
#pragma unroll
                for (int ni = 0; ni < 4; ni++)
                    acc[mi][ni] = __builtin_amdgcn_mfma_f32_16x16x32_bf16(
                        af[mi], bfr[ni], acc[mi][ni], 0, 0, 0);
        }

        // epilogue: C/D layout col = lane&15 (N), row = quad*4 + r (M)
#pragma unroll
        for (int mi = 0; mi < 4; mi++) {
#pragma unroll
            for (int r = 0; r < 4; r++) {
                const int grow = m0 + wm + mi * 16 + quad * 4 + r;
                const float bv = bias[grow];
#pragma unroll
                for (int ni = 0; ni < 4; ni++) {
                    const int gcol = n0 + wn + ni * 16 + tcol;
                    float v = acc[mi][ni][r] + bv;
                    if (SECOND) {
                        const int n = gcol & 4095;
                        const size_t oidx = ((size_t)(b * 256 + grow)) * 4096 + n;
                        ((float*)Cout)[oidx] = v + xres[oidx];
                    } else {
                        ((__bf16*)Cout)[(size_t)grow * 65536 + gcol] = (__bf16)v;
                    }
                }
            }
        }
    }
}

// ---------------------------------------------------------------------------
// q softmax over n (4096) — one block per (o,b) row, in place on qkv rows 0..255
// ---------------------------------------------------------------------------
__global__ __launch_bounds__(256)
void softmax_q(__bf16* __restrict__ qkv)
{
    const int o = blockIdx.x >> 4;
    const int b = blockIdx.x & 15;
    const int tid = threadIdx.x;
    const int lane = tid & 63, wid = tid >> 6;
    const size_t base = (size_t)o * 65536 + (size_t)b * 4096;

    float v[16];
    float m = -INFINITY;
#pragma unroll
    for (int s = 0; s < 16; s++) {
        v[s] = (float)qkv[base + s * 256 + tid];
        m = fmaxf(m, v[s]);
    }
    __shared__ float red[4];
    float wmx = wave_red_max(m);
    if (lane == 0) red[wid] = wmx;
    __syncthreads();
    m = fmaxf(fmaxf(red[0], red[1]), fmaxf(red[2], red[3]));
    __syncthreads();
    float sum = 0.f;
#pragma unroll
    for (int s = 0; s < 16; s++) { v[s] = __expf(v[s] - m); sum += v[s]; }
    float wsm = wave_red_sum(sum);
    if (lane == 0) red[wid] = wsm;
    __syncthreads();
    const float inv = 1.0f / (red[0] + red[1] + red[2] + red[3]);
#pragma unroll
    for (int s = 0; s < 16; s++)
        qkv[base + s * 256 + tid] = (__bf16)(v[s] * inv);
}

// ---------------------------------------------------------------------------
// ctx[bh][e][d] = sum_n v[e][n] * softmax_d(k)[d][n]; k-softmax fused in-tile.
// grid 512 = (bh 64) x (kc 8); block 256; per block n-range = 512
// ---------------------------------------------------------------------------
__global__ __launch_bounds__(256)
void ctx_sm_kernel(const __bf16* __restrict__ qkv, float* __restrict__ ctx)
{
    const int bh = blockIdx.x >> 3, kc = blockIdx.x & 7;
    const int b = bh >> 2, hh = bh & 3;
    const int n_start = kc * 512;
    __shared__ __align__(16) __bf16 lk[64 * 68], lv[64 * 68];
    __shared__ float smax[4][64], ssum[4][64];
    const int tid = threadIdx.x;
    const int te = tid & 15, td = tid >> 4;
    const int e0 = te * 4, d0 = td * 4;
    const int col = tid & 63, dq = tid >> 6;
    float acc[4][4] = {};

    const size_t kbase = (size_t)(256 + hh * 64) * 65536 + (size_t)b * 4096;
    const size_t vbase = (size_t)(512 + hh * 64) * 65536 + (size_t)b * 4096;
    const int sd = tid >> 2, sn = (tid & 3) * 16;

    for (int nc = 0; nc < 512; nc += 64) {
        __syncthreads();
        {   // stage raw k and v tiles [64 d][64 n]
            const __bf16* ks = qkv + kbase + (size_t)sd * 65536 + n_start + nc + sn;
            bf16x8 a0 = *(const bf16x8*)ks, a1 = *(const bf16x8*)(ks + 8);
            *(bf16x8*)&lk[sd * 68 + sn]     = a0;
            *(bf16x8*)&lk[sd * 68 + sn + 8] = a1;
            const __bf16* vs = qkv + vbase + (size_t)sd * 65536 + n_start + nc + sn;
            bf16x8 c0 = *(const bf16x8*)vs, c1 = *(const bf16x8*)(vs + 8);
            *(bf16x8*)&lv[sd * 68 + sn]     = c0;
            *(bf16x8*)&lv[sd * 68 + sn + 8] = c1;
        }
        __syncthreads();

        // fused k-softmax over d (full d=64 lives in this tile per column)
        float kvv[16];
        float pm = -INFINITY;
#pragma unroll
        for (int i = 0; i < 16; i++) {
            kvv[i] = (float)lk[(dq * 16 + i) * 68 + col];
            pm = fmaxf(pm, kvv[i]);
        }
        smax[dq][col] = pm;
        __syncthreads();
        const float m = fmaxf(fmaxf(smax[0][col], smax[1][col]),
                              fmaxf(smax[2][col], smax[3][col]));
        float ps = 0.f;
#pragma unroll
        for (int i = 0; i < 16; i++) { kvv[i] = __expf(kvv[i] - m); ps += kvv[i]; }
        ssum[dq][col] = ps;
        __syncthreads();
        const float inv = 1.0f / (ssum[0][col] + ssum[1][col] + ssum[2][col] + ssum[3][col]);
#pragma unroll
        for (int i = 0; i < 16; i++)
            lk[(dq * 16 + i) * 68 + col] = (__bf16)(kvv[i] * inv);
        __syncthreads();

        // outer-product accumulate: acc[e][d] += v[e][n] * k[d][n]
#pragma unroll
        for (int n4 = 0; n4 < 64; n4 += 4) {
            bf16x4 kq[4], vq[4];
#pragma unroll
            for (int j = 0; j < 4; j++) {
                kq[j] = *(const bf16x4*)&lk[(d0 + j) * 68 + n4];
                vq[j] = *(const bf16x4*)&lv[(e0 + j) * 68 + n4];
            }
            float kf[4][4], vf[4][4];
#pragma unroll
            for (int j = 0; j < 4; j++)
#pragma unroll
                for (int t = 0; t < 4; t++) {
                    kf[j][t] = (float)kq[j][t];
                    vf[j][t] = (float)vq[j][t];
                }
#pragma unroll
            for (int i = 0; i < 4; i++)
#pragma unroll
                for (int j = 0; j < 4; j++)
#pragma unroll
                    for (int t = 0; t < 4; t++)
                        acc[i][j] += vf[i][t] * kf[j][t];
        }
    }
    float* cb = ctx + (size_t)bh * 4096;
#pragma unroll
    for (int i = 0; i < 4; i++)
#pragma unroll
        for (int j = 0; j < 4; j++)
            atomicAdd(&cb[(e0 + i) * 64 + (d0 + j)], acc[i][j]);
}

// ---------------------------------------------------------------------------
// W2[b][o][h*64+d] = sum_e out_w[o][h*64+e] * ctx[bh][e][d]   (bf16 out)
// grid 64 = (b 16) x (h 4); block 256 (one thread per o)
// ---------------------------------------------------------------------------
__global__ __launch_bounds__(256)
void w2_kernel(const float* __restrict__ ctx, const float* __restrict__ out_w,
               __bf16* __restrict__ w2)
{
    const int bh = blockIdx.x;
    const int b = bh >> 2, hh = bh & 3;
    const int tid = threadIdx.x;

    __shared__ __align__(16) float lctx[4096];
    const float* csrc = ctx + (size_t)bh * 4096;
#pragma unroll
    for (int i = 0; i < 4; i++)
        ((float4*)lctx)[tid + i * 256] = ((const float4*)csrc)[tid + i * 256];
    __syncthreads();

    float acc[64];
#pragma unroll
    for (int d = 0; d < 64; d++) acc[d] = 0.f;

    const float* wrow = out_w + (size_t)tid * 256 + hh * 64;
    for (int e = 0; e < 64; e++) {
        const float w = wrow[e];
#pragma unroll
        for (int d4 = 0; d4 < 64; d4 += 4) {
            const float4 c4 = *(const float4*)&lctx[e * 64 + d4];
            acc[d4 + 0] += w * c4.x;
            acc[d4 + 1] += w * c4.y;
            acc[d4 + 2] += w * c4.z;
            acc[d4 + 3] += w * c4.w;
        }
    }
    __bf16* dst = w2 + (size_t)b * 65536 + (size_t)tid * 256 + hh * 64;
#pragma unroll
    for (int d4 = 0; d4 < 64; d4 += 4) {
        bf16x4 t;
        t[0] = (__bf16)acc[d4 + 0]; t[1] = (__bf16)acc[d4 + 1];
        t[2] = (__bf16)acc[d4 + 2]; t[3] = (__bf16)acc[d4 + 3];
        *(bf16x4*)(dst + d4) = t;
    }
}

// ---------------------------------------------------------------------------
extern "C" void kernel_launch(void* const* d_in, const int* in_sizes, int n_in,
                              void* d_out, int out_size, void* d_ws, size_t ws_size,
                              hipStream_t stream)
{
    const float* x     = (const float*)d_in[0];
    const float* gn_w  = (const float*)d_in[1];
    const float* gn_b  = (const float*)d_in[2];
    const float* qkv_w = (const float*)d_in[3];
    const float* qkv_b = (const float*)d_in[4];
    const float* out_w = (const float*)d_in[5];
    const float* out_b = (const float*)d_in[6];
    float* out = (float*)d_out;

    char* ws = (char*)d_ws;
    __bf16* qkv  = (__bf16*)ws;                                   // 100,663,296 B
    float*  ctx  = (float*)(ws + (size_t)100663296);              //   1,048,576 B
    float2* scsh = (float2*)(ws + (size_t)100663296 + 1048576);   //      32,768 B
    __bf16* w2   = qkv + (size_t)256 * 65536;                     // dead k-rows

    hipMemsetAsync(ctx, 0, 262144 * sizeof(float), stream);
    gn_stats_kernel<<<512, 256, 0, stream>>>(x, gn_w, gn_b, scsh);
    gemm_kernel<false><<<512, 256, 0, stream>>>(qkv_w, x, qkv_b, nullptr, scsh, qkv);
    softmax_q<<<4096, 256, 0, stream>>>(qkv);
    ctx_sm_kernel<<<512, 256, 0, stream>>>(qkv, ctx);
    w2_kernel<<<64, 256, 0, stream>>>(ctx, out_w, w2);
    gemm_kernel<true><<<512, 256, 0, stream>>>(w2, qkv, out_b, x, nullptr, out);
}

// Round 5
// 279.151 us; speedup vs baseline: 1.4307x; 1.2468x over previous
//
#include <hip/hip_runtime.h>

// B=16, C=256, H=W=64 -> N=4096, NH=4, HD=64, G=32 (8 ch/group), K=256
// ALL inputs and d_out are FP32. Internal: bf16 operands + fp32 acc.
// qkv rows: o in [0,768): q=[0,256), k=[256,512), v=[512,768)
// Workspace:
//   qkv  : (o, b*N + n) 768 x 65536 bf16 = 100,663,296 B at +0
//   ctx  : (b*4+h,e,d)  64 x 64 x 64 f32 =   1,048,576 B at +100663296
//   scsh : (b,c) float2                  =      32,768 B at +101711872
//   qst  : (o,b) float2 256x16           =      32,768 B at +101744640
//   wbf  : qkv_w bf16 768x256            =     393,216 B at +101777408
//   W2   : (b,o,c') 16x256x256 bf16 (2MB) reuses dead k-rows (+33554432)
// Pipeline: gn_stats -> wcast -> gemm1(GN fused, 3072 blk) -> qstats
//           -> ctx_mfma(k-softmax fused) -> w2 -> gemm2(q-softmax fused)

typedef __bf16 bf16x8 __attribute__((ext_vector_type(8)));
typedef __bf16 bf16x4 __attribute__((ext_vector_type(4)));
typedef float  f32x4  __attribute__((ext_vector_type(4)));

__device__ __forceinline__ float wave_red_sum(float v) {
#pragma unroll
    for (int off = 32; off > 0; off >>= 1) v += __shfl_xor(v, off, 64);
    return v;
}
__device__ __forceinline__ float wave_red_max(float v) {
#pragma unroll
    for (int off = 32; off > 0; off >>= 1) v = fmaxf(v, __shfl_xor(v, off, 64));
    return v;
}

// ---------------------------------------------------------------------------
// GroupNorm stats -> per-channel (sc, sh); grid 512 = (b16 x g32), block 256
// ---------------------------------------------------------------------------
__global__ __launch_bounds__(256)
void gn_stats_kernel(const float* __restrict__ x, const float* __restrict__ gw,
                     const float* __restrict__ gb, float2* __restrict__ scsh)
{
    const int blk = blockIdx.x;
    const int b = blk >> 5, g = blk & 31;
    const int tid = threadIdx.x;
    const int lane = tid & 63, wid = tid >> 6;
    const size_t xbase = ((size_t)(b * 256 + g * 8)) * 4096;

    float s1 = 0.f, s2 = 0.f;
#pragma unroll
    for (int it = 0; it < 32; it++) {
        const int idx = (it * 256 + tid) * 4;
        const float4 v4 = *(const float4*)(x + xbase + idx);
        s1 += v4.x + v4.y + v4.z + v4.w;
        s2 += v4.x * v4.x + v4.y * v4.y + v4.z * v4.z + v4.w * v4.w;
    }
    __shared__ float red[8];
    float s1w = wave_red_sum(s1);
    float s2w = wave_red_sum(s2);
    if (lane == 0) { red[wid] = s1w; red[4 + wid] = s2w; }
    __syncthreads();
    const float mean = (red[0] + red[1] + red[2] + red[3]) * (1.0f / 32768.0f);
    const float ms   = (red[4] + red[5] + red[6] + red[7]) * (1.0f / 32768.0f);
    const float inv  = rsqrtf(fmaxf(ms - mean * mean, 0.f) + 1e-5f);

    if (tid < 8) {
        const int c = g * 8 + tid;
        const float sc = gw[c] * inv;
        const float sh = gb[c] - mean * sc;
        scsh[b * 256 + c] = make_float2(sc, sh);
    }
}

// ---------------------------------------------------------------------------
// Cast qkv_w fp32 -> bf16; 196608 elems; grid 192, block 256, 4/thread
// ---------------------------------------------------------------------------
__global__ __launch_bounds__(256)
void wcast_kernel(const float* __restrict__ w, __bf16* __restrict__ wb)
{
    const int i = (blockIdx.x * 256 + threadIdx.x) * 4;
    const float4 f = *(const float4*)(w + i);
    bf16x4 t;
    t[0] = (__bf16)f.x; t[1] = (__bf16)f.y; t[2] = (__bf16)f.z; t[3] = (__bf16)f.w;
    *(bf16x4*)(wb + i) = t;
}

// ---------------------------------------------------------------------------
// gemm1: qkv[o][bn] = sum_c wbf[o][c] * gn(x)[c][bn] + bias.
// Grid (512 n-tiles, 6 m-tiles); block 256 (4 waves); tile 128x128, BK=32.
// LDS 18.4 KB -> 4+ blocks/CU. A and B both in chunk-swizzled [row][32] LDS:
//   elem (r, k): byte = r*64 + ((kchunk + ((r>>1)&3))&3)*16 + (k&7)*2
// giving ~conflict-free ds_write_b128 staging AND ds_read_b128 fragments.
// ---------------------------------------------------------------------------
__global__ __launch_bounds__(256)
void gemm1_kernel(const __bf16* __restrict__ wbf,
                  const float* __restrict__ x,
                  const float* __restrict__ bias,
                  const float2* __restrict__ scsh,
                  __bf16* __restrict__ qkv)
{
    __shared__ __align__(16) char lds_a[8192];
    __shared__ __align__(16) char lds_b[8192];
    __shared__ float2 lscsh[256];

    const int tid  = threadIdx.x;
    const int lane = tid & 63;
    const int wid  = tid >> 6;
    const int quad = lane >> 4;
    const int tcol = lane & 15;
    const int wm   = (wid & 1) * 64;
    const int wn   = (wid >> 1) * 64;
    const int n0   = blockIdx.x * 128;
    const int m0   = blockIdx.y * 128;
    const int b    = n0 >> 12;
    const int nn   = n0 & 4095;

    lscsh[tid] = scsh[b * 256 + tid];

    const int sn  = tid & 127;    // B staging: column n (0..127)
    const int sth = tid >> 7;     // B staging: c-half (0/1)
    const int am  = tid >> 1;     // A staging: row m (0..127)
    const int ah  = tid & 1;      // A staging: k-half (0/1)

    f32x4 acc[4][4];
#pragma unroll
    for (int i = 0; i < 4; i++)
#pragma unroll
        for (int j = 0; j < 4; j++) acc[i][j] = {0.f, 0.f, 0.f, 0.f};

    const float* xcol = x + (size_t)b * 1048576 + nn + sn;
    const int aswz = (am >> 1) & 3;
    const int bswz = (sn >> 1) & 3;

    for (int kt = 0; kt < 256; kt += 32) {
        __syncthreads();
        {   // stage A tile 128x32 (bf16 already)
            const __bf16* asrc = wbf + (m0 + am) * 256 + kt + ah * 16;
            const bf16x8 a0 = *(const bf16x8*)asrc;
            const bf16x8 a1 = *(const bf16x8*)(asrc + 8);
            *(bf16x8*)&lds_a[am * 64 + (((ah * 2)     + aswz) & 3) * 16] = a0;
            *(bf16x8*)&lds_a[am * 64 + (((ah * 2 + 1) + aswz) & 3) * 16] = a1;
        }
        {   // stage B tile 128n x 32c from fp32 x with fused GroupNorm
            const float* xs = xcol + (size_t)(kt + sth * 16) * 4096;
            bf16x8 o0, o1;
#pragma unroll
            for (int j = 0; j < 16; j++) {
                const float2 ss = lscsh[kt + sth * 16 + j];
                const float f = xs[(size_t)j * 4096];
                const __bf16 v = (__bf16)(f * ss.x + ss.y);
                if (j < 8) o0[j] = v; else o1[j - 8] = v;
            }
            *(bf16x8*)&lds_b[sn * 64 + (((sth * 2)     + bswz) & 3) * 16] = o0;
            *(bf16x8*)&lds_b[sn * 64 + (((sth * 2 + 1) + bswz) & 3) * 16] = o1;
        }
        __syncthreads();

        bf16x8 af[4], bfr[4];
#pragma unroll
        for (int mi = 0; mi < 4; mi++) {
            const int m = wm + mi * 16 + tcol;
            af[mi] = *(const bf16x8*)&lds_a[m * 64 + ((quad + ((m >> 1) & 3)) & 3) * 16];
        }
#pragma unroll
        for (int ni = 0; ni < 4; ni++) {
            const int n = wn + ni * 16 + tcol;
            bfr[ni] = *(const bf16x8*)&lds_b[n * 64 + ((quad + ((n >> 1) & 3)) & 3) * 16];
        }
#pragma unroll
        for (int mi = 0; mi < 4; mi++)
#pragma unroll
            for (int ni = 0; ni < 4; ni++)
                acc[mi][ni] = __builtin_amdgcn_mfma_f32_16x16x32_bf16(
                    af[mi], bfr[ni], acc[mi][ni], 0, 0, 0);
    }

    // epilogue: C/D layout col = lane&15 (N), row = quad*4 + r (M)
#pragma unroll
    for (int mi = 0; mi < 4; mi++) {
#pragma unroll
        for (int r = 0; r < 4; r++) {
            const int grow = m0 + wm + mi * 16 + quad * 4 + r;
            const float bv = bias[grow];
#pragma unroll
            for (int ni = 0; ni < 4; ni++) {
                const int gcol = n0 + wn + ni * 16 + tcol;
                qkv[(size_t)grow * 65536 + gcol] = (__bf16)(acc[mi][ni][r] + bv);
            }
        }
    }
}

// ---------------------------------------------------------------------------
// qstats: per (o,b) row of q: (max, 1/sum(exp)) -> qst[o*16+b]
// grid 4096 = (o 256) x (b 16); block 256
// ---------------------------------------------------------------------------
__global__ __launch_bounds__(256)
void qstats_kernel(const __bf16* __restrict__ qkv, float2* __restrict__ qst)
{
    const int o = blockIdx.x >> 4;
    const int b = blockIdx.x & 15;
    const int tid = threadIdx.x;
    const int lane = tid & 63, wid = tid >> 6;
    const size_t base = (size_t)o * 65536 + (size_t)b * 4096;

    float v[16];
    float m = -INFINITY;
#pragma unroll
    for (int s = 0; s < 16; s++) {
        v[s] = (float)qkv[base + s * 256 + tid];
        m = fmaxf(m, v[s]);
    }
    __shared__ float red[4];
    float wmx = wave_red_max(m);
    if (lane == 0) red[wid] = wmx;
    __syncthreads();
    m = fmaxf(fmaxf(red[0], red[1]), fmaxf(red[2], red[3]));
    __syncthreads();
    float sum = 0.f;
#pragma unroll
    for (int s = 0; s < 16; s++) sum += __expf(v[s] - m);
    float wsm = wave_red_sum(sum);
    if (lane == 0) red[wid] = wsm;
    __syncthreads();
    if (tid == 0)
        qst[o * 16 + b] = make_float2(m, 1.0f / (red[0] + red[1] + red[2] + red[3]));
}

// ---------------------------------------------------------------------------
// ctx[bh][e][d] = sum_n v[e][n] * softmax_d(k)[d][n] via MFMA.
// grid 512 = (bh 64) x (kc 8); block 256 (4 waves, each owns a 32x32 quadrant)
// ---------------------------------------------------------------------------
__global__ __launch_bounds__(256)
void ctx_mfma_kernel(const __bf16* __restrict__ qkv, float* __restrict__ ctx)
{
    const int bh = blockIdx.x >> 3, kc = blockIdx.x & 7;
    const int b = bh >> 2, hh = bh & 3;
    __shared__ __align__(16) __bf16 lk[64 * 72], lv[64 * 72];
    __shared__ float smax[4][64], ssum[4][64];
    const int tid = threadIdx.x;
    const int lane = tid & 63, wid = tid >> 6;
    const int quad = lane >> 4, tcol = lane & 15;
    const int eh = (wid & 1) * 32, dh = (wid >> 1) * 32;
    const int col = tid & 63, dq = tid >> 6;
    const int sd = tid >> 2, snn = (tid & 3) * 16;

    f32x4 acc[2][2];
#pragma unroll
    for (int i = 0; i < 2; i++)
#pragma unroll
        for (int j = 0; j < 2; j++) acc[i][j] = {0.f, 0.f, 0.f, 0.f};

    const size_t kbase = (size_t)(256 + hh * 64) * 65536 + (size_t)b * 4096 + kc * 512;
    const size_t vbase = (size_t)(512 + hh * 64) * 65536 + (size_t)b * 4096 + kc * 512;

    for (int nc = 0; nc < 512; nc += 64) {
        __syncthreads();
        {   // stage k,v tiles [64 ch][64 n], row stride 72
            const __bf16* ks = qkv + kbase + (size_t)sd * 65536 + nc + snn;
            *(bf16x8*)&lk[sd * 72 + snn]     = *(const bf16x8*)ks;
            *(bf16x8*)&lk[sd * 72 + snn + 8] = *(const bf16x8*)(ks + 8);
            const __bf16* vs = qkv + vbase + (size_t)sd * 65536 + nc + snn;
            *(bf16x8*)&lv[sd * 72 + snn]     = *(const bf16x8*)vs;
            *(bf16x8*)&lv[sd * 72 + snn + 8] = *(const bf16x8*)(vs + 8);
        }
        __syncthreads();

        // fused k-softmax over d (full d=64 in tile per column)
        float kvv[16];
        float pm = -INFINITY;
#pragma unroll
        for (int i = 0; i < 16; i++) {
            kvv[i] = (float)lk[(dq * 16 + i) * 72 + col];
            pm = fmaxf(pm, kvv[i]);
        }
        smax[dq][col] = pm;
        __syncthreads();
        const float m = fmaxf(fmaxf(smax[0][col], smax[1][col]),
                              fmaxf(smax[2][col], smax[3][col]));
        float ps = 0.f;
#pragma unroll
        for (int i = 0; i < 16; i++) { kvv[i] = __expf(kvv[i] - m); ps += kvv[i]; }
        ssum[dq][col] = ps;
        __syncthreads();
        const float inv = 1.0f / (ssum[0][col] + ssum[1][col] + ssum[2][col] + ssum[3][col]);
#pragma unroll
        for (int i = 0; i < 16; i++)
            lk[(dq * 16 + i) * 72 + col] = (__bf16)(kvv[i] * inv);
        __syncthreads();

        // MFMA: D[e][d] += sum_n v[e][n] * k_sm[d][n]
#pragma unroll
        for (int k2 = 0; k2 < 64; k2 += 32) {
            bf16x8 af[2], bfr[2];
#pragma unroll
            for (int mi = 0; mi < 2; mi++)
                af[mi] = *(const bf16x8*)&lv[(eh + mi * 16 + tcol) * 72 + k2 + quad * 8];
#pragma unroll
            for (int ni = 0; ni < 2; ni++)
                bfr[ni] = *(const bf16x8*)&lk[(dh + ni * 16 + tcol) * 72 + k2 + quad * 8];
#pragma unroll
            for (int mi = 0; mi < 2; mi++)
#pragma unroll
                for (int ni = 0; ni < 2; ni++)
                    acc[mi][ni] = __builtin_amdgcn_mfma_f32_16x16x32_bf16(
                        af[mi], bfr[ni], acc[mi][ni], 0, 0, 0);
        }
    }
    float* cb = ctx + (size_t)bh * 4096;
#pragma unroll
    for (int mi = 0; mi < 2; mi++)
#pragma unroll
        for (int ni = 0; ni < 2; ni++)
#pragma unroll
            for (int r = 0; r < 4; r++) {
                const int e = eh + mi * 16 + quad * 4 + r;
                const int d = dh + ni * 16 + tcol;
                atomicAdd(&cb[e * 64 + d], acc[mi][ni][r]);
            }
}

// ---------------------------------------------------------------------------
// W2[b][o][h*64+d] = sum_e out_w[o][h*64+e] * ctx[bh][e][d]   (bf16 out)
// grid 64 = (b 16) x (h 4); block 256 (one thread per o)
// ---------------------------------------------------------------------------
__global__ __launch_bounds__(256)
void w2_kernel(const float* __restrict__ ctx, const float* __restrict__ out_w,
               __bf16* __restrict__ w2)
{
    const int bh = blockIdx.x;
    const int b = bh >> 2, hh = bh & 3;
    const int tid = threadIdx.x;

    __shared__ __align__(16) float lctx[4096];
    const float* csrc = ctx + (size_t)bh * 4096;
#pragma unroll
    for (int i = 0; i < 4; i++)
        ((float4*)lctx)[tid + i * 256] = ((const float4*)csrc)[tid + i * 256];
    __syncthreads();

    float acc[64];
#pragma unroll
    for (int d = 0; d < 64; d++) acc[d] = 0.f;

    const float* wrow = out_w + (size_t)tid * 256 + hh * 64;
    for (int e = 0; e < 64; e++) {
        const float w = wrow[e];
#pragma unroll
        for (int d4 = 0; d4 < 64; d4 += 4) {
            const float4 c4 = *(const float4*)&lctx[e * 64 + d4];
            acc[d4 + 0] += w * c4.x;
            acc[d4 + 1] += w * c4.y;
            acc[d4 + 2] += w * c4.z;
            acc[d4 + 3] += w * c4.w;
        }
    }
    __bf16* dst = w2 + (size_t)b * 65536 + (size_t)tid * 256 + hh * 64;
#pragma unroll
    for (int d4 = 0; d4 < 64; d4 += 4) {
        bf16x4 t;
        t[0] = (__bf16)acc[d4 + 0]; t[1] = (__bf16)acc[d4 + 1];
        t[2] = (__bf16)acc[d4 + 2]; t[3] = (__bf16)acc[d4 + 3];
        *(bf16x4*)(dst + d4) = t;
    }
}

// ---------------------------------------------------------------------------
// gemm2: out[b][o][n] = sum_c W2[b][o][c] * softmax_n(q)[c][bn] + out_b + x.
// Round-4 proven structure: full-K B^T in LDS, MT=2; q-softmax fused into
// B^T staging using qstats. grid 512 n-tiles; block 256.
// ---------------------------------------------------------------------------
__global__ __launch_bounds__(256)
void gemm2_kernel(const __bf16* __restrict__ w2,
                  const __bf16* __restrict__ qkv,
                  const float2* __restrict__ qst,
                  const float* __restrict__ bias,
                  const float* __restrict__ xres,
                  float* __restrict__ out)
{
    __shared__ __align__(16) __bf16 lds_bt[128 * 264];  // B^T: [n][k], 67584 B
    __shared__ __align__(16) __bf16 lds_a[128 * 40];    // A:   [m][k], 10240 B
    __shared__ float2 lqst[256];

    const int tid  = threadIdx.x;
    const int lane = tid & 63;
    const int wid  = tid >> 6;
    const int quad = lane >> 4;
    const int tcol = lane & 15;
    const int wm   = (wid & 1) * 64;
    const int wn   = (wid >> 1) * 64;
    const int n0   = blockIdx.x * 128;
    const int b    = n0 >> 12;

    lqst[tid] = qst[tid * 16 + b];
    __syncthreads();

    const int sn    = tid & 127;
    const int chalf = tid >> 7;
    const int swz   = (sn >> 3) & 3;
#pragma unroll
    for (int iter = 0; iter < 8; iter++) {
        const int cbase = iter * 32 + chalf * 16;
        bf16x8 o0, o1;
        const __bf16* qs = qkv + n0 + sn;
#pragma unroll
        for (int j = 0; j < 16; j++) {
            const int c = cbase + j;
            const float2 qq = lqst[c];
            const float f = (float)qs[(size_t)c * 65536];
            const __bf16 v = (__bf16)(__expf(f - qq.x) * qq.y);
            if (j < 8) o0[j] = v; else o1[j - 8] = v;
        }
        const int chunk = iter * 2 + chalf;
        const int chSw  = chunk ^ swz;
        __bf16* dst = &lds_bt[sn * 264 + chSw * 16];
        *(bf16x8*)dst       = o0;
        *(bf16x8*)(dst + 8) = o1;
    }

    const int arow = tid >> 1, k16 = (tid & 1) * 16;

    for (int mt = 0; mt < 2; mt++) {
        const int m0 = mt * 128;
        f32x4 acc[4][4];
#pragma unroll
        for (int i = 0; i < 4; i++)
#pragma unroll
            for (int j = 0; j < 4; j++) acc[i][j] = {0.f, 0.f, 0.f, 0.f};

        for (int kt = 0; kt < 256; kt += 32) {
            __syncthreads();
            {   // stage A tile 128x32 from W2[b] (bf16)
                const __bf16* src = w2 + (size_t)b * 65536
                                  + (size_t)(m0 + arow) * 256 + kt + k16;
                const bf16x8 o0 = *(const bf16x8*)(src);
                const bf16x8 o1 = *(const bf16x8*)(src + 8);
                *(bf16x8*)&lds_a[arow * 40 + k16]     = o0;
                *(bf16x8*)&lds_a[arow * 40 + k16 + 8] = o1;
            }
            __syncthreads();

            bf16x8 af[4];
#pragma unroll
            for (int mi = 0; mi < 4; mi++)
                af[mi] = *(const bf16x8*)&lds_a[(wm + mi * 16 + tcol) * 40 + quad * 8];
            bf16x8 bfr[4];
#pragma unroll
            for (int ni = 0; ni < 4; ni++) {
                const int n = wn + ni * 16 + tcol;
                const int k = kt + quad * 8;
                const int chSw = (k >> 4) ^ ((n >> 3) & 3);
                bfr[ni] = *(const bf16x8*)&lds_bt[n * 264 + chSw * 16 + (k & 15)];
            }
#pragma unroll
            for (int mi = 0; mi < 4; mi++)
#pragma unroll
                for (int ni = 0; ni < 4; ni++)
                    acc[mi][ni] = __builtin_amdgcn_mfma_f32_16x16x32_bf16(
                        af[mi], bfr[ni], acc[mi][ni], 0, 0, 0);
        }

#pragma unroll
        for (int mi = 0; mi < 4; mi++) {
#pragma unroll
            for (int r = 0; r < 4; r++) {
                const int grow = m0 + wm + mi * 16 + quad * 4 + r;
                const float bv = bias[grow];
#pragma unroll
                for (int ni = 0; ni < 4; ni++) {
                    const int gcol = n0 + wn + ni * 16 + tcol;
                    const int n = gcol & 4095;
                    const size_t oidx = ((size_t)(b * 256 + grow)) * 4096 + n;
                    out[oidx] = acc[mi][ni][r] + bv + xres[oidx];
                }
            }
        }
    }
}

// ---------------------------------------------------------------------------
extern "C" void kernel_launch(void* const* d_in, const int* in_sizes, int n_in,
                              void* d_out, int out_size, void* d_ws, size_t ws_size,
                              hipStream_t stream)
{
    const float* x     = (const float*)d_in[0];
    const float* gn_w  = (const float*)d_in[1];
    const float* gn_b  = (const float*)d_in[2];
    const float* qkv_w = (const float*)d_in[3];
    const float* qkv_b = (const float*)d_in[4];
    const float* out_w = (const float*)d_in[5];
    const float* out_b = (const float*)d_in[6];
    float* out = (float*)d_out;

    char* ws = (char*)d_ws;
    __bf16* qkv  = (__bf16*)ws;                                   // 100,663,296 B
    float*  ctx  = (float*)(ws + (size_t)100663296);              //   1,048,576 B
    float2* scsh = (float2*)(ws + (size_t)101711872);             //      32,768 B
    float2* qst  = (float2*)(ws + (size_t)101744640);             //      32,768 B
    __bf16* wbf  = (__bf16*)(ws + (size_t)101777408);             //     393,216 B
    __bf16* w2   = qkv + (size_t)256 * 65536;                     // dead k rows

    hipMemsetAsync(ctx, 0, 262144 * sizeof(float), stream);
    gn_stats_kernel<<<512, 256, 0, stream>>>(x, gn_w, gn_b, scsh);
    wcast_kernel<<<192, 256, 0, stream>>>(qkv_w, wbf);
    gemm1_kernel<<<dim3(512, 6), 256, 0, stream>>>(wbf, x, qkv_b, scsh, qkv);
    qstats_kernel<<<4096, 256, 0, stream>>>(qkv, qst);
    ctx_mfma_kernel<<<512, 256, 0, stream>>>(qkv, ctx);
    w2_kernel<<<64, 256, 0, stream>>>(ctx, out_w, w2);
    gemm2_kernel<<<512, 256, 0, stream>>>(w2, qkv, qst, out_b, x, out);
}